// Round 10
// baseline (105.900 us; speedup 1.0000x reference)
//
#include <hip/hip_runtime.h>
#include <math.h>

// native clang vector types (required by __builtin_nontemporal_*)
typedef float fx4 __attribute__((ext_vector_type(4)));
typedef float fx2 __attribute__((ext_vector_type(2)));

// ---- cross-lane helpers ----
// partner value at lane^8 via DPP row_ror:8 (VALU pipe; 16-lane row, rot 8 == xor 8)
__device__ __forceinline__ float DPP8(float x) {
    int t = __builtin_amdgcn_update_dpp(0, __float_as_int(x), 0x128, 0xf, 0xf, false);
    return __int_as_float(t);
}
#define SWZ16(x) __int_as_float(__builtin_amdgcn_ds_swizzle(__float_as_int(x), 0x401F)) // lane^16
#define SX32(x)  __shfl_xor((x), 32)

#define K1_NPW 2   // nodes per wave in k1 (sequential, NOT unrolled)
#define K2_NPW 8   // nodes per wave in k2 (4 pairs)

// ============================================================================
// K1: fused LayerNorm + both input projections. K1_NPW nodes per wave,
// processed STRICTLY SEQUENTIALLY (unroll 1) to preserve per-node load order
// and cache-line locality (r9 lesson: cross-node load interleaving + nt
// evict-first policy => 2.5x read amplification).
// lane = (cg = lane>>3 owns 16 channels, kq = lane&7 owns output k)
// ============================================================================
__global__ __launch_bounds__(256, 4) void k1_ln_proj(
    const float* __restrict__ s_feats,
    const float* __restrict__ ln_w,   // (2,128)
    const float* __restrict__ ln_b,   // (128)
    const float* __restrict__ w_in,   // (256,8)
    float* __restrict__ ys,           // (N,64)
    int N)
{
    const int lane = threadIdx.x & 63;
    const int kq = lane & 7;
    const int cg = lane >> 3;
    const int w = blockIdx.x * 4 + (threadIdx.x >> 6);

    // per-lane constant weights: w_in premultiplied by ln scale rows
    float wa0[16], wa1[16], wb0[16], wb1[16];
    float B1 = 0.f, C1 = 0.f, B2 = 0.f, C2 = 0.f;
    #pragma unroll
    for (int t = 0; t < 16; t++) {
        int c = cg * 16 + t;
        float w1 = w_in[c * 8 + kq];
        float w2 = w_in[(128 + c) * 8 + kq];
        float l0 = ln_w[c], l1 = ln_w[128 + c], lb = ln_b[c];
        wa0[t] = w1 * l0; wa1[t] = w1 * l1;
        wb0[t] = w2 * l0; wb1[t] = w2 * l1;
        B1 += w1 * l0; C1 += lb * w1;
        B2 += w2 * l0; C2 += lb * w2;
    }
    B1 += DPP8(B1);  C1 += DPP8(C1);  B2 += DPP8(B2);  C2 += DPP8(C2);
    B1 += SWZ16(B1); C1 += SWZ16(C1); B2 += SWZ16(B2); C2 += SWZ16(C2);
    B1 += SX32(B1);  C1 += SX32(C1);  B2 += SX32(B2);  C2 += SX32(C2);

    const int n0 = w * K1_NPW;
    // lane-permutation source for monotonic store
    const int src = ((lane >> 2) & 7) + ((lane & 3) << 3) + (lane & 32);

    #pragma unroll 1
    for (int u = 0; u < K1_NPW; u++) {
        int n = n0 + u;
        if (n >= N) break;
        const float* sp = s_feats + (size_t)n * 512 + cg * 16;
        float accY[4] = {0.f, 0.f, 0.f, 0.f};
        float accS[4] = {0.f, 0.f, 0.f, 0.f};
        float ssum = 0.f, sq0 = 0.f, sq1 = 0.f;
        #pragma unroll
        for (int m = 0; m < 4; m++) {
            #pragma unroll
            for (int i = 0; i < 4; i++) {
                fx4 v = __builtin_nontemporal_load((const fx4*)(sp + m * 128 + i * 4));
                float e0 = v.x, e1 = v.y, e2 = v.z, e3 = v.w;
                if (m == 0) {
                    accY[0] += e0 * wa0[i*4+0] + e1 * wa0[i*4+1] + e2 * wa0[i*4+2] + e3 * wa0[i*4+3];
                    accS[0] += e0 * wb0[i*4+0] + e1 * wb0[i*4+1] + e2 * wb0[i*4+2] + e3 * wb0[i*4+3];
                    ssum += e0 + e1 + e2 + e3;
                    sq0  += e0 * e0 + e1 * e1 + e2 * e2 + e3 * e3;
                } else {
                    accY[m] += e0 * wa1[i*4+0] + e1 * wa1[i*4+1] + e2 * wa1[i*4+2] + e3 * wa1[i*4+3];
                    accS[m] += e0 * wb1[i*4+0] + e1 * wb1[i*4+1] + e2 * wb1[i*4+2] + e3 * wb1[i*4+3];
                    sq1  += e0 * e0 + e1 * e1 + e2 * e2 + e3 * e3;
                }
            }
        }
        #define RED_ALL(FN) \
            accY[0] += FN(accY[0]); accY[1] += FN(accY[1]); accY[2] += FN(accY[2]); accY[3] += FN(accY[3]); \
            accS[0] += FN(accS[0]); accS[1] += FN(accS[1]); accS[2] += FN(accS[2]); accS[3] += FN(accS[3]); \
            ssum += FN(ssum); sq0 += FN(sq0); sq1 += FN(sq1);
        RED_ALL(DPP8)
        RED_ALL(SWZ16)
        RED_ALL(SX32)
        #undef RED_ALL

        float mean = ssum * (1.0f / 128.0f);
        float r0 = rsqrtf((sq0 - ssum * mean) * (1.0f / 128.0f) + 1e-5f);
        float r1 = rsqrtf(sq1 * (1.0f / 128.0f) + 1e-5f);

        float aA = (cg & 2) ? ((cg & 1) ? accY[3] : accY[2]) : ((cg & 1) ? accY[1] : accY[0]);
        float aB = (cg & 2) ? ((cg & 1) ? accS[3] : accS[2]) : ((cg & 1) ? accS[1] : accS[0]);
        float av = (cg & 4) ? aB : aA;
        float Bv = (cg & 4) ? B2 : B1;
        float Cv = (cg & 4) ? C2 : C1;
        bool isM0 = (cg & 3) == 0;
        float outv = isM0 ? (r0 * (av - mean * Bv) + Cv) : (r1 * av);

        // monotonic store: lane L writes element L
        float myv = __shfl(outv, src);
        ys[(size_t)n * 64 + lane] = myv;
    }
}

// ============================================================================
// K2: per-edge tensor product + fused w_out epilogue. 8 nodes/wave (4 pairs).
// lane = (h = lane>>3, k = lane&7). All weights in registers; fx4 stores.
// ============================================================================
#define TROW 40

__global__ __launch_bounds__(256, 3) void k2_edges(
    const float* __restrict__ ys,       // (N,64)
    const float* __restrict__ s_points, // (N,3)
    const int*   __restrict__ nbr,      // (N,9)
    const float* __restrict__ w0,       // (16,16)
    const float* __restrict__ wr,       // (8,8)
    const float* __restrict__ wi,       // (8,8)
    const float* __restrict__ w_out,    // (8,128)
    float* __restrict__ out,            // (N,4,128)
    int N)
{
    __shared__ float tbuf[8][8 * TROW];
    __shared__ float abuf[8][32];

    const int tid = threadIdx.x;
    const int lane = tid & 63;
    const int h = lane >> 3, k = lane & 7;
    const int wv = tid >> 6;
    const int w = blockIdx.x * 4 + wv;
    const int base = w * K2_NPW;

    // ---- mixing weights in registers ----
    float c00[8], c08[8], c10[8], c18[8], cwr[8], cwi[8];
    #pragma unroll
    for (int j = 0; j < 8; j++) {
        c00[j] = w0[j * 16 + k];
        c08[j] = w0[(8 + j) * 16 + k];
        c10[j] = w0[j * 16 + 8 + k];
        c18[j] = w0[(8 + j) * 16 + 8 + k];
        cwr[j] = wr[j * 8 + k];
        cwi[j] = wi[j * 8 + k];
    }
    // ---- epilogue weights: lane -> m-pair (lane>>5), channels c0..c0+3 ----
    const int c0 = 4 * (lane & 31);
    const bool hi = lane >= 32;
    fx4 wo[8];
    #pragma unroll
    for (int kk = 0; kk < 8; kk++)
        wo[kk] = *(const fx4*)&w_out[kk * 128 + c0];

    if (base >= N) return;

    auto node_compute = [&](int slot, int nn, float PX, float PY, float PZ,
                            float NX, float NY, float NZ, fx4 YV, fx4 SV) {
        float vx = NX - PX, vy = NY - PY, vz = NZ - PZ;
        float nrm = sqrtf(vx * vx + vy * vy + vz * vz);
        float inv = 1.0f / (nrm + 1e-9f);
        float ux = vx * inv, uy = vy * inv, uz = vz * inv;
        float cz = uz;
        float kx = uy, ky = -ux;
        bool safe = cz > -0.999f;
        float idd = safe ? 1.0f / (1.0f + cz) : 1.0f;
        float D00, D01, D02, D10, D11, D12, D20, D21, D22;
        {
            float R00, R01, R02, R10, R11, R12, R20, R21, R22;
            if (safe) {
                R00 = 1.0f - ky * ky * idd; R01 = kx * ky * idd;        R02 = ky;
                R10 = kx * ky * idd;        R11 = 1.0f - kx * kx * idd; R12 = -kx;
                R20 = -ky;                  R21 = kx;                   R22 = 1.0f - (kx * kx + ky * ky) * idd;
            } else {
                R00 = 1.0f; R01 = 0.0f; R02 = 0.0f;
                R10 = 0.0f; R11 = -1.0f; R12 = 0.0f;
                R20 = 0.0f; R21 = 0.0f; R22 = -1.0f;
            }
            D00 = R11; D01 = R12; D02 = R10;
            D10 = R21; D11 = R22; D12 = R20;
            D20 = R01; D21 = R02; D22 = R00;
        }
        float msg0 = YV.x + SV.x, msg1 = YV.y + SV.y, msg2 = YV.z + SV.z, msg3 = YV.w + SV.w;
        float l1_0 = D00 * msg1 + D01 * msg2 + D02 * msg3;
        float l1_1 = D10 * msg1 + D11 * msg2 + D12 * msg3;
        float l1_2 = D20 * msg1 + D21 * msg2 + D22 * msg3;

        *(fx4*)&tbuf[slot][h * TROW + k * 4] = (fx4){msg0, l1_0, l1_1, l1_2};

        float m00 = 0.f, m01 = 0.f, ypl = 0.f, yml = 0.f;
        #pragma unroll
        for (int j = 0; j < 8; j++) {
            fx4 t = *(const fx4*)&tbuf[slot][h * TROW + j * 4];
            m00 += t.x * c00[j] + t.z * c08[j];
            m01 += t.x * c10[j] + t.z * c18[j];
            ypl += t.w * cwr[j] - t.y * cwi[j];
            yml += t.y * cwr[j] + t.w * cwi[j];
        }
        float f0 = m00;
        float f1 = D00 * yml + D10 * m01 + D20 * ypl;
        float f2 = D01 * yml + D11 * m01 + D21 * ypl;
        float f3 = D02 * yml + D12 * m01 + D22 * ypl;

        f0 += DPP8(f0);  f1 += DPP8(f1);  f2 += DPP8(f2);  f3 += DPP8(f3);
        f0 += SWZ16(f0); f1 += SWZ16(f1); f2 += SWZ16(f2); f3 += SWZ16(f3);
        f0 += SX32(f0);  f1 += SX32(f1);  f2 += SX32(f2);  f3 += SX32(f3);

        if (h == 0)
            *(fx4*)&abuf[slot][k * 4] = (fx4){f0, f1, f2, f3};

        // fused epilogue: lane covers m in {mb, mb+1}, channels c0..c0+3
        fx4 olo = {0.f, 0.f, 0.f, 0.f}, ohi = {0.f, 0.f, 0.f, 0.f};
        #pragma unroll
        for (int kk = 0; kk < 8; kk++) {
            fx4 a = *(const fx4*)&abuf[slot][kk * 4];   // broadcast read
            float am0 = hi ? a.z : a.x;
            float am1 = hi ? a.w : a.y;
            olo += am0 * wo[kk];
            ohi += am1 * wo[kk];
        }
        float* op = out + (size_t)nn * 512 + (hi ? 256 : 0);
        *(fx4*)(op + c0)       = olo;   // m = mb   row
        *(fx4*)(op + 128 + c0) = ohi;   // m = mb+1 row
    };

    #pragma unroll
    for (int p = 0; p < K2_NPW / 2; p++) {
        int n0 = base + 2 * p;
        if (n0 >= N) break;
        int n1 = n0 + 1;
        bool v1 = n1 < N;

        // phase A: chain heads
        int idx0 = nbr[n0 * 9 + 1 + h];
        int idx1 = v1 ? nbr[n1 * 9 + 1 + h] : 0x7fffffff;
        bool mk0 = idx0 < N, mk1 = idx1 < N;

        // phase B: all gathers for the pair, batched
        float px0 = s_points[n0 * 3], py0 = s_points[n0 * 3 + 1], pz0 = s_points[n0 * 3 + 2];
        float px1 = v1 ? s_points[n1 * 3]     : 0.f;
        float py1 = v1 ? s_points[n1 * 3 + 1] : 0.f;
        float pz1 = v1 ? s_points[n1 * 3 + 2] : 0.f;
        float nx0 = mk0 ? s_points[idx0 * 3]     : 0.f;
        float ny0 = mk0 ? s_points[idx0 * 3 + 1] : 0.f;
        float nz0 = mk0 ? s_points[idx0 * 3 + 2] : 0.f;
        float nx1 = mk1 ? s_points[idx1 * 3]     : 0.f;
        float ny1 = mk1 ? s_points[idx1 * 3 + 1] : 0.f;
        float nz1 = mk1 ? s_points[idx1 * 3 + 2] : 0.f;
        fx4 yv0 = mk0 ? *(const fx4*)(ys + (size_t)idx0 * 64 + k * 4) : (fx4){0.f,0.f,0.f,0.f};
        fx4 yv1 = mk1 ? *(const fx4*)(ys + (size_t)idx1 * 64 + k * 4) : (fx4){0.f,0.f,0.f,0.f};
        fx4 sv0 = *(const fx4*)(ys + (size_t)n0 * 64 + 32 + k * 4);
        fx4 sv1 = v1 ? *(const fx4*)(ys + (size_t)n1 * 64 + 32 + k * 4) : (fx4){0.f,0.f,0.f,0.f};

        node_compute(wv * 2 + 0, n0, px0, py0, pz0, nx0, ny0, nz0, yv0, sv0);
        if (v1)
            node_compute(wv * 2 + 1, n1, px1, py1, pz1, nx1, ny1, nz1, yv1, sv1);
    }
}

extern "C" void kernel_launch(void* const* d_in, const int* in_sizes, int n_in,
                              void* d_out, int out_size, void* d_ws, size_t ws_size,
                              hipStream_t stream) {
    const float* s_feats  = (const float*)d_in[0];
    const float* s_points = (const float*)d_in[1];
    const int*   nbr      = (const int*)d_in[2];
    const float* ln_w     = (const float*)d_in[3];
    const float* ln_b     = (const float*)d_in[4];
    const float* w_in     = (const float*)d_in[5];
    const float* w_out    = (const float*)d_in[6];
    const float* so2_w0   = (const float*)d_in[7];
    const float* so2_wr   = (const float*)d_in[8];
    const float* so2_wi   = (const float*)d_in[9];
    float* out = (float*)d_out;

    int N = in_sizes[0] / 512;
    float* ys = (float*)d_ws;   // N*64 floats

    int nb1 = (N + 4 * K1_NPW - 1) / (4 * K1_NPW);   // 2 nodes/wave, 4 waves/block
    int nb2 = (N + 4 * K2_NPW - 1) / (4 * K2_NPW);   // 8 nodes/wave, 4 waves/block
    k1_ln_proj<<<nb1, 256, 0, stream>>>(s_feats, ln_w, ln_b, w_in, ys, N);
    k2_edges<<<nb2, 256, 0, stream>>>(ys, s_points, nbr, so2_w0, so2_wr, so2_wi,
                                      w_out, out, N);
}

// Round 11
// 60.257 us; speedup vs baseline: 1.7575x; 1.7575x over previous
//
#include <hip/hip_runtime.h>
#include <math.h>

// native clang vector types (required by __builtin_nontemporal_*)
typedef float fx4 __attribute__((ext_vector_type(4)));
typedef float fx2 __attribute__((ext_vector_type(2)));

// ---- cross-lane helpers (LDS-pipe ds_swizzle, single instruction) ----
#define SWZ8(x)  __int_as_float(__builtin_amdgcn_ds_swizzle(__float_as_int(x), 0x201F)) // lane^8
#define SWZ16(x) __int_as_float(__builtin_amdgcn_ds_swizzle(__float_as_int(x), 0x401F)) // lane^16
#define SX32(x)  __shfl_xor((x), 32)
// partner value at lane^8 via DPP row_ror:8 (VALU pipe)
__device__ __forceinline__ float DPP8(float x) {
    int t = __builtin_amdgcn_update_dpp(0, __float_as_int(x), 0x128, 0xf, 0xf, false);
    return __int_as_float(t);
}

#define K2_NPW 8   // nodes per wave in k2 (4 pairs)

// ============================================================================
// K1: fused LayerNorm + both input projections. ONE node per wave (pure TLP —
// r7/r9/r10 ablation: 20000 waves beats any per-wave amortization for this
// latency-bound kernel). lane = (cg = lane>>3, kq = lane&7).
// ============================================================================
__global__ __launch_bounds__(256, 4) void k1_ln_proj(
    const float* __restrict__ s_feats,
    const float* __restrict__ ln_w,   // (2,128)
    const float* __restrict__ ln_b,   // (128)
    const float* __restrict__ w_in,   // (256,8)
    float* __restrict__ ys,           // (N,64)
    int N)
{
    const int lane = threadIdx.x & 63;
    const int kq = lane & 7;
    const int cg = lane >> 3;
    const int n = blockIdx.x * 4 + (threadIdx.x >> 6);

    // per-lane constant weights: w_in premultiplied by ln scale rows
    float wa0[16], wa1[16], wb0[16], wb1[16];
    float B1 = 0.f, C1 = 0.f, B2 = 0.f, C2 = 0.f;
    #pragma unroll
    for (int t = 0; t < 16; t++) {
        int c = cg * 16 + t;
        float w1 = w_in[c * 8 + kq];
        float w2 = w_in[(128 + c) * 8 + kq];
        float l0 = ln_w[c], l1 = ln_w[128 + c], lb = ln_b[c];
        wa0[t] = w1 * l0; wa1[t] = w1 * l1;
        wb0[t] = w2 * l0; wb1[t] = w2 * l1;
        B1 += w1 * l0; C1 += lb * w1;
        B2 += w2 * l0; C2 += lb * w2;
    }
    B1 += SWZ8(B1);  C1 += SWZ8(C1);  B2 += SWZ8(B2);  C2 += SWZ8(C2);
    B1 += SWZ16(B1); C1 += SWZ16(C1); B2 += SWZ16(B2); C2 += SWZ16(C2);
    B1 += SX32(B1);  C1 += SX32(C1);  B2 += SX32(B2);  C2 += SX32(C2);

    if (n >= N) return;

    const float* sp = s_feats + (size_t)n * 512 + cg * 16;
    float accY[4] = {0.f, 0.f, 0.f, 0.f};
    float accS[4] = {0.f, 0.f, 0.f, 0.f};
    float ssum = 0.f, sq0 = 0.f, sq1 = 0.f;
    #pragma unroll
    for (int m = 0; m < 4; m++) {
        #pragma unroll
        for (int i = 0; i < 4; i++) {
            fx4 v = __builtin_nontemporal_load((const fx4*)(sp + m * 128 + i * 4));
            float e0 = v.x, e1 = v.y, e2 = v.z, e3 = v.w;
            if (m == 0) {
                accY[0] += e0 * wa0[i*4+0] + e1 * wa0[i*4+1] + e2 * wa0[i*4+2] + e3 * wa0[i*4+3];
                accS[0] += e0 * wb0[i*4+0] + e1 * wb0[i*4+1] + e2 * wb0[i*4+2] + e3 * wb0[i*4+3];
                ssum += e0 + e1 + e2 + e3;
                sq0  += e0 * e0 + e1 * e1 + e2 * e2 + e3 * e3;
            } else {
                accY[m] += e0 * wa1[i*4+0] + e1 * wa1[i*4+1] + e2 * wa1[i*4+2] + e3 * wa1[i*4+3];
                accS[m] += e0 * wb1[i*4+0] + e1 * wb1[i*4+1] + e2 * wb1[i*4+2] + e3 * wb1[i*4+3];
                sq1  += e0 * e0 + e1 * e1 + e2 * e2 + e3 * e3;
            }
        }
    }
    #define RED_ALL(FN) \
        accY[0] += FN(accY[0]); accY[1] += FN(accY[1]); accY[2] += FN(accY[2]); accY[3] += FN(accY[3]); \
        accS[0] += FN(accS[0]); accS[1] += FN(accS[1]); accS[2] += FN(accS[2]); accS[3] += FN(accS[3]); \
        ssum += FN(ssum); sq0 += FN(sq0); sq1 += FN(sq1);
    RED_ALL(SWZ8)
    RED_ALL(SWZ16)
    RED_ALL(SX32)
    #undef RED_ALL

    float mean = ssum * (1.0f / 128.0f);
    float r0 = rsqrtf((sq0 - ssum * mean) * (1.0f / 128.0f) + 1e-5f);
    float r1 = rsqrtf(sq1 * (1.0f / 128.0f) + 1e-5f);

    float aA = (cg & 2) ? ((cg & 1) ? accY[3] : accY[2]) : ((cg & 1) ? accY[1] : accY[0]);
    float aB = (cg & 2) ? ((cg & 1) ? accS[3] : accS[2]) : ((cg & 1) ? accS[1] : accS[0]);
    float av = (cg & 4) ? aB : aA;
    float Bv = (cg & 4) ? B2 : B1;
    float Cv = (cg & 4) ? C2 : C1;
    bool isM0 = (cg & 3) == 0;
    float outv = isM0 ? (r0 * (av - mean * Bv) + Cv) : (r1 * av);

    // monotonic store: lane L writes element L (r7: kills write amplification)
    int src = ((lane >> 2) & 7) + ((lane & 3) << 3) + (lane & 32);
    float myv = __shfl(outv, src);
    ys[(size_t)n * 64 + lane] = myv;
}

// ============================================================================
// K2: per-edge tensor product + fused w_out epilogue. 8 nodes/wave (4 pairs).
// lane = (h = lane>>3, k = lane&7). All weights in registers; fx4 stores.
// ============================================================================
#define TROW 40

__global__ __launch_bounds__(256, 3) void k2_edges(
    const float* __restrict__ ys,       // (N,64)
    const float* __restrict__ s_points, // (N,3)
    const int*   __restrict__ nbr,      // (N,9)
    const float* __restrict__ w0,       // (16,16)
    const float* __restrict__ wr,       // (8,8)
    const float* __restrict__ wi,       // (8,8)
    const float* __restrict__ w_out,    // (8,128)
    float* __restrict__ out,            // (N,4,128)
    int N)
{
    __shared__ float tbuf[8][8 * TROW];
    __shared__ float abuf[8][32];

    const int tid = threadIdx.x;
    const int lane = tid & 63;
    const int h = lane >> 3, k = lane & 7;
    const int wv = tid >> 6;
    const int w = blockIdx.x * 4 + wv;
    const int base = w * K2_NPW;

    // ---- mixing weights in registers ----
    float c00[8], c08[8], c10[8], c18[8], cwr[8], cwi[8];
    #pragma unroll
    for (int j = 0; j < 8; j++) {
        c00[j] = w0[j * 16 + k];
        c08[j] = w0[(8 + j) * 16 + k];
        c10[j] = w0[j * 16 + 8 + k];
        c18[j] = w0[(8 + j) * 16 + 8 + k];
        cwr[j] = wr[j * 8 + k];
        cwi[j] = wi[j * 8 + k];
    }
    // ---- epilogue weights: lane -> m-pair (lane>>5), channels c0..c0+3 ----
    const int c0 = 4 * (lane & 31);
    const bool hi = lane >= 32;
    fx4 wo[8];
    #pragma unroll
    for (int kk = 0; kk < 8; kk++)
        wo[kk] = *(const fx4*)&w_out[kk * 128 + c0];

    if (base >= N) return;

    auto node_compute = [&](int slot, int nn, float PX, float PY, float PZ,
                            float NX, float NY, float NZ, fx4 YV, fx4 SV) {
        float vx = NX - PX, vy = NY - PY, vz = NZ - PZ;
        float nrm = sqrtf(vx * vx + vy * vy + vz * vz);
        float inv = 1.0f / (nrm + 1e-9f);
        float ux = vx * inv, uy = vy * inv, uz = vz * inv;
        float cz = uz;
        float kx = uy, ky = -ux;
        bool safe = cz > -0.999f;
        float idd = safe ? 1.0f / (1.0f + cz) : 1.0f;
        float D00, D01, D02, D10, D11, D12, D20, D21, D22;
        {
            float R00, R01, R02, R10, R11, R12, R20, R21, R22;
            if (safe) {
                R00 = 1.0f - ky * ky * idd; R01 = kx * ky * idd;        R02 = ky;
                R10 = kx * ky * idd;        R11 = 1.0f - kx * kx * idd; R12 = -kx;
                R20 = -ky;                  R21 = kx;                   R22 = 1.0f - (kx * kx + ky * ky) * idd;
            } else {
                R00 = 1.0f; R01 = 0.0f; R02 = 0.0f;
                R10 = 0.0f; R11 = -1.0f; R12 = 0.0f;
                R20 = 0.0f; R21 = 0.0f; R22 = -1.0f;
            }
            D00 = R11; D01 = R12; D02 = R10;
            D10 = R21; D11 = R22; D12 = R20;
            D20 = R01; D21 = R02; D22 = R00;
        }
        float msg0 = YV.x + SV.x, msg1 = YV.y + SV.y, msg2 = YV.z + SV.z, msg3 = YV.w + SV.w;
        float l1_0 = D00 * msg1 + D01 * msg2 + D02 * msg3;
        float l1_1 = D10 * msg1 + D11 * msg2 + D12 * msg3;
        float l1_2 = D20 * msg1 + D21 * msg2 + D22 * msg3;

        *(fx4*)&tbuf[slot][h * TROW + k * 4] = (fx4){msg0, l1_0, l1_1, l1_2};

        float m00 = 0.f, m01 = 0.f, ypl = 0.f, yml = 0.f;
        #pragma unroll
        for (int j = 0; j < 8; j++) {
            fx4 t = *(const fx4*)&tbuf[slot][h * TROW + j * 4];
            m00 += t.x * c00[j] + t.z * c08[j];
            m01 += t.x * c10[j] + t.z * c18[j];
            ypl += t.w * cwr[j] - t.y * cwi[j];
            yml += t.y * cwr[j] + t.w * cwi[j];
        }
        float f0 = m00;
        float f1 = D00 * yml + D10 * m01 + D20 * ypl;
        float f2 = D01 * yml + D11 * m01 + D21 * ypl;
        float f3 = D02 * yml + D12 * m01 + D22 * ypl;

        f0 += DPP8(f0);  f1 += DPP8(f1);  f2 += DPP8(f2);  f3 += DPP8(f3);
        f0 += SWZ16(f0); f1 += SWZ16(f1); f2 += SWZ16(f2); f3 += SWZ16(f3);
        f0 += SX32(f0);  f1 += SX32(f1);  f2 += SX32(f2);  f3 += SX32(f3);

        if (h == 0)
            *(fx4*)&abuf[slot][k * 4] = (fx4){f0, f1, f2, f3};

        // fused epilogue: lane covers m in {mb, mb+1}, channels c0..c0+3
        fx4 olo = {0.f, 0.f, 0.f, 0.f}, ohi = {0.f, 0.f, 0.f, 0.f};
        #pragma unroll
        for (int kk = 0; kk < 8; kk++) {
            fx4 a = *(const fx4*)&abuf[slot][kk * 4];   // broadcast read
            float am0 = hi ? a.z : a.x;
            float am1 = hi ? a.w : a.y;
            olo += am0 * wo[kk];
            ohi += am1 * wo[kk];
        }
        float* op = out + (size_t)nn * 512 + (hi ? 256 : 0);
        *(fx4*)(op + c0)       = olo;   // m = mb   row
        *(fx4*)(op + 128 + c0) = ohi;   // m = mb+1 row
    };

    #pragma unroll
    for (int p = 0; p < K2_NPW / 2; p++) {
        int n0 = base + 2 * p;
        if (n0 >= N) break;
        int n1 = n0 + 1;
        bool v1 = n1 < N;

        // phase A: chain heads
        int idx0 = nbr[n0 * 9 + 1 + h];
        int idx1 = v1 ? nbr[n1 * 9 + 1 + h] : 0x7fffffff;
        bool mk0 = idx0 < N, mk1 = idx1 < N;

        // phase B: all gathers for the pair, batched
        float px0 = s_points[n0 * 3], py0 = s_points[n0 * 3 + 1], pz0 = s_points[n0 * 3 + 2];
        float px1 = v1 ? s_points[n1 * 3]     : 0.f;
        float py1 = v1 ? s_points[n1 * 3 + 1] : 0.f;
        float pz1 = v1 ? s_points[n1 * 3 + 2] : 0.f;
        float nx0 = mk0 ? s_points[idx0 * 3]     : 0.f;
        float ny0 = mk0 ? s_points[idx0 * 3 + 1] : 0.f;
        float nz0 = mk0 ? s_points[idx0 * 3 + 2] : 0.f;
        float nx1 = mk1 ? s_points[idx1 * 3]     : 0.f;
        float ny1 = mk1 ? s_points[idx1 * 3 + 1] : 0.f;
        float nz1 = mk1 ? s_points[idx1 * 3 + 2] : 0.f;
        fx4 yv0 = mk0 ? *(const fx4*)(ys + (size_t)idx0 * 64 + k * 4) : (fx4){0.f,0.f,0.f,0.f};
        fx4 yv1 = mk1 ? *(const fx4*)(ys + (size_t)idx1 * 64 + k * 4) : (fx4){0.f,0.f,0.f,0.f};
        fx4 sv0 = *(const fx4*)(ys + (size_t)n0 * 64 + 32 + k * 4);
        fx4 sv1 = v1 ? *(const fx4*)(ys + (size_t)n1 * 64 + 32 + k * 4) : (fx4){0.f,0.f,0.f,0.f};

        node_compute(wv * 2 + 0, n0, px0, py0, pz0, nx0, ny0, nz0, yv0, sv0);
        if (v1)
            node_compute(wv * 2 + 1, n1, px1, py1, pz1, nx1, ny1, nz1, yv1, sv1);
    }
}

extern "C" void kernel_launch(void* const* d_in, const int* in_sizes, int n_in,
                              void* d_out, int out_size, void* d_ws, size_t ws_size,
                              hipStream_t stream) {
    const float* s_feats  = (const float*)d_in[0];
    const float* s_points = (const float*)d_in[1];
    const int*   nbr      = (const int*)d_in[2];
    const float* ln_w     = (const float*)d_in[3];
    const float* ln_b     = (const float*)d_in[4];
    const float* w_in     = (const float*)d_in[5];
    const float* w_out    = (const float*)d_in[6];
    const float* so2_w0   = (const float*)d_in[7];
    const float* so2_wr   = (const float*)d_in[8];
    const float* so2_wi   = (const float*)d_in[9];
    float* out = (float*)d_out;

    int N = in_sizes[0] / 512;
    float* ys = (float*)d_ws;   // N*64 floats

    int nb1 = (N + 3) / 4;                           // k1: 1 node/wave (max TLP)
    int nb2 = (N + 4 * K2_NPW - 1) / (4 * K2_NPW);   // k2: 8 nodes/wave
    k1_ln_proj<<<nb1, 256, 0, stream>>>(s_feats, ln_w, ln_b, w_in, ys, N);
    k2_edges<<<nb2, 256, 0, stream>>>(ys, s_points, nbr, so2_w0, so2_wr, so2_wi,
                                      w_out, out, N);
}